// Round 10
// baseline (39.997 us; speedup 1.0000x reference)
//
#include <hip/hip_runtime.h>
#include <math.h>

#define K_TOP 16
#define D_DIM 1024
#define N_ROWS 2048                       // 32 * 64 rows

typedef float f32x4 __attribute__((ext_vector_type(4)));

// ---------------- K1: selection -> workspace ------------------------------
// One wave per row q = blockIdx.x*4 + wave. Lane owns d = lane*16+j
// (coalesced f32x4 loads). 16 rounds of {per-lane masked argmax ->
// 64-lane butterfly argmax}, tie-break prefers smaller global index.
// Rank-sort ascending by index; lanes 0..15 write ws[q*16 + rank] = index.
__global__ __launch_bounds__(256) void select_kernel(
    const float* __restrict__ logits,  // (64, 1024)
    const float* __restrict__ gn,      // (32, 64, 1024)
    int* __restrict__ ws)              // (2048, 16) winner indices
{
    const int tid  = threadIdx.x;
    const int lane = tid & 63;
    const int wave = tid >> 6;
    const int q    = blockIdx.x * 4 + wave;
    const int r    = q & 63;

    // ---- load + perturb: lane owns 16 consecutive elements (64 B) ----
    float v[16];
    {
        const f32x4* l4 = reinterpret_cast<const f32x4*>(
            logits + (size_t)r * D_DIM + lane * 16);
        const f32x4* g4 = reinterpret_cast<const f32x4*>(
            gn + (size_t)q * D_DIM + lane * 16);
        #pragma unroll
        for (int c = 0; c < 4; ++c) {
            const f32x4 a = l4[c];
            const f32x4 b = g4[c];
            v[c * 4 + 0] = a.x + b.x;
            v[c * 4 + 1] = a.y + b.y;
            v[c * 4 + 2] = a.z + b.z;
            v[c * 4 + 3] = a.w + b.w;
        }
    }

    // ---- 16 rounds of wave-wide argmax ----
    unsigned chosen = 0;   // bitmask of already-taken j's in THIS lane
    int my_sel = 0;        // lane k ends up holding round-k winner's index
    for (int round = 0; round < K_TOP; ++round) {
        float bv = -INFINITY;
        int   bi = 0x7fffffff;
        #pragma unroll
        for (int j = 0; j < 16; ++j) {
            if (!(chosen & (1u << j))) {
                // strict > keeps smaller j (= smaller index) on ties
                if (v[j] > bv) { bv = v[j]; bi = lane * 16 + j; }
            }
        }
        #pragma unroll
        for (int off = 32; off > 0; off >>= 1) {
            const float ov = __shfl_xor(bv, off);
            const int   oi = __shfl_xor(bi, off);
            if (ov > bv || (ov == bv && oi < bi)) { bv = ov; bi = oi; }
        }
        if (lane == (bi >> 4)) chosen |= 1u << (bi & 15);  // owner retires it
        if (lane == round)     my_sel = bi;
    }

    // ---- rank among the 16 winners = ascending index order ----
    int rank = 0;
    #pragma unroll
    for (int j = 0; j < K_TOP; ++j) {
        const int other = __shfl(my_sel, j);
        rank += (other < my_sel) ? 1 : 0;
    }

    if (lane < K_TOP) ws[q * K_TOP + rank] = my_sel;
}

// ---------------- K2: pure streaming merged one-hot fill ------------------
// One block per row q. Wave w owns k-rows w*4..w*4+3. Four wave-uniform
// scalar loads of the winners (ws is 128 KB, L2-resident), then 16 x 1KB
// f32x4 stores with the 1.0 merged in. No barriers, no scatter, no LDS.
__global__ __launch_bounds__(256) void fill_kernel(
    const int* __restrict__ ws,        // (2048, 16)
    float* __restrict__ out)           // (32, 64, 16, 1024)
{
    const int tid  = threadIdx.x;
    const int lane = tid & 63;
    const int wave = tid >> 6;
    const int q    = blockIdx.x;
    const int kbase = wave * 4;

    const int* selp = ws + q * K_TOP + kbase;
    const int s0 = selp[0], s1 = selp[1], s2 = selp[2], s3 = selp[3];

    f32x4* o4 = reinterpret_cast<f32x4*>(out + (size_t)q * (K_TOP * D_DIM))
              + kbase * 256;
    const f32x4 zero = {0.f, 0.f, 0.f, 0.f};

    int sel[4];
    sel[0] = s0; sel[1] = s1; sel[2] = s2; sel[3] = s3;
    #pragma unroll
    for (int kk = 0; kk < 4; ++kk) {
        const int s  = sel[kk];          // wave-uniform
        const int sv = s >> 2;           // which f32x4 holds the 1
        f32x4 hot;
        hot.x = ((s & 3) == 0) ? 1.0f : 0.0f;
        hot.y = ((s & 3) == 1) ? 1.0f : 0.0f;
        hot.z = ((s & 3) == 2) ? 1.0f : 0.0f;
        hot.w = ((s & 3) == 3) ? 1.0f : 0.0f;
        f32x4* krow = o4 + kk * 256;
        #pragma unroll
        for (int c = 0; c < 4; ++c) {
            const int f4idx = c * 64 + lane;
            krow[f4idx] = (f4idx == sv) ? hot : zero;
        }
    }
}

extern "C" void kernel_launch(void* const* d_in, const int* in_sizes, int n_in,
                              void* d_out, int out_size, void* d_ws, size_t ws_size,
                              hipStream_t stream) {
    const float* logits = (const float*)d_in[0];  // (64, 1024) f32
    const float* gn     = (const float*)d_in[1];  // (32, 64, 1024) f32
    float* out          = (float*)d_out;          // (32, 64, 16, 1024) f32
    int*   ws           = (int*)d_ws;             // 2048*16 ints = 128 KB

    // K1: top-16 select + rank per row -> ws.
    select_kernel<<<dim3(N_ROWS / 4), dim3(256), 0, stream>>>(logits, gn, ws);
    // K2: streaming merged one-hot fill (runs after K1 on stream).
    fill_kernel<<<dim3(N_ROWS), dim3(256), 0, stream>>>(ws, out);
}